// Round 4
// baseline (236.137 us; speedup 1.0000x reference)
//
#include <hip/hip_runtime.h>

// LongformerAttention on MI355X (gfx950), fp16 MFMA pipeline, round 11.
// R11: R10's attn win (stage-ahead dbuf + counted vmcnt, -27us) applied to
// both GEMMs, at BK=32 so staging LDS stays 32 KB (2x16) and co-residency
// stays 4 blocks/CU (R8's regression came from 72KB LDS halving occupancy).
// Per K-tile: stage(t+1)->other buf (4 global_load_lds/thread); vmcnt(4)
// (tile t's loads issued a full tile earlier -> near-zero wait, t+1 in
// flight); raw s_barrier; 8 ds_read_b128 + 16 MFMA (compiler lgkmcnt);
// lgkmcnt(0)+sched_barrier+s_barrier. No __syncthreads in hot loop (it
// drains vmcnt(0) - the m97 stall that capped MfmaUtil at 33%).
// BK=32 swizzle: store chunk c=(p&3)^(r&3)^((r>>2)&1); read slot
// quad^(l4&3)^((l4>>2)&1) - 2-way max on b128 16-lane sub-passes (free).
// Attn/convert unchanged from R10.

typedef _Float16 half8 __attribute__((ext_vector_type(8)));
typedef _Float16 half4v __attribute__((ext_vector_type(4)));
typedef float floatx4 __attribute__((ext_vector_type(4)));

typedef __attribute__((address_space(3))) unsigned int lds_u32;
typedef const __attribute__((address_space(1))) unsigned int glb_u32;

__device__ __forceinline__ void async_copy16(const void* g, void* l) {
  // global -> LDS direct, 16 B/lane. LDS dest = wave-uniform base + lane*16.
  __builtin_amdgcn_global_load_lds((glb_u32*)g, (lds_u32*)l, 16, 0, 0);
}

// ---------------------------------------------------------------- convert
__global__ __launch_bounds__(256) void convert_kernel(
    const float* __restrict__ x, const float* __restrict__ wq,
    const float* __restrict__ wk, const float* __restrict__ wv,
    const float* __restrict__ wo, _Float16* __restrict__ dst) {
  const int e0 = (blockIdx.x * 256 + threadIdx.x) * 4;
  const float* src; int off;
  if      (e0 <  8388608) { src = x;  off = e0; }
  else if (e0 <  9437184) { src = wq; off = e0 -  8388608; }
  else if (e0 < 10485760) { src = wk; off = e0 -  9437184; }
  else if (e0 < 11534336) { src = wv; off = e0 - 10485760; }
  else                    { src = wo; off = e0 - 11534336; }
  const float4 f = *(const float4*)(src + off);
  half4v h;
  h[0] = (_Float16)f.x; h[1] = (_Float16)f.y;
  h[2] = (_Float16)f.z; h[3] = (_Float16)f.w;
  *(half4v*)(dst + e0) = h;
}

// ---------------------------------------------------------------- QKV GEMM
// out[m,n] = sum_k A[m,k]*W[n,k] + bias[n]; RoPE fused in epilogue for q,k
// (pair (n,n^1) in adjacent l4 lanes -> __shfl_xor(val,1)); q scaled log2e/8.
// z==2 (V): epilogue LDS tile stored transposed, output written as V^T
// [bh][d][s] directly.
// R11 main loop: BK=32, double-buffered (2x16KB), stage-ahead + vmcnt(4).
__global__ __launch_bounds__(256, 2) void gemm_qkv_kernel(
    const _Float16* __restrict__ A, const _Float16* __restrict__ w0,
    const _Float16* __restrict__ w1, const _Float16* __restrict__ w2,
    const float* __restrict__ b0, const float* __restrict__ b1,
    const float* __restrict__ b2, _Float16* __restrict__ o0,
    _Float16* __restrict__ o1, _Float16* __restrict__ o2) {
  __shared__ _Float16 smem[17408];          // 2 bufs 2x8192 / epi tile 16896

  const int tid = threadIdx.x;
  const int w = tid >> 6, lane = tid & 63;
  const int l4 = lane & 15, quad = lane >> 4;
  const int wm = w & 1, wn = w >> 1;

  const int bid = blockIdx.x;
  const int xcd = bid & 7, li = bid >> 3;   // li in 0..191
  const int z = li >> 6, r_ = li & 63;
  const int n_l = r_ >> 3, m_l = r_ & 7;
  const int m0 = (xcd * 8 + m_l) * 128;
  const int n0 = n_l * 128;

  const _Float16* B; const float* bias; _Float16* out;
  if (z == 0)      { B = w0; bias = b0; out = o0; }
  else if (z == 1) { B = w1; bias = b1; out = o1; }
  else             { B = w2; bias = b2; out = o2; }
  const bool dorope = z < 2;
  const float scl = (z == 0) ? 0.18033688f : 1.0f;  // log2e/8

  // staging offsets: position p = i*256+tid, row r = p>>2 (4 chunks/row of 8
  // halfs), phys chunk c = (p&3)^(r&3)^((r>>2)&1)  (2-way-free read swizzle)
  int aoff[2], boff[2];
#pragma unroll
  for (int i = 0; i < 2; ++i) {
    const int p = i * 256 + tid;
    const int r = p >> 2;
    const int c = (p & 3) ^ (r & 3) ^ ((r >> 2) & 1);
    aoff[i] = (m0 + r) * 1024 + c * 8;
    boff[i] = (n0 + r) * 1024 + c * 8;
  }
  const int ldst = w * 512;                 // wave-uniform dest (halfs)

  auto stage = [&](int b_, int kt) {        // 4 loads/thread: A(2) + B(2)
    _Float16* Ad = smem + b_ * 8192;
    _Float16* Bd = Ad + 4096;
    const int k0 = kt * 32;
#pragma unroll
    for (int i = 0; i < 2; ++i) {
      async_copy16(A + aoff[i] + k0, Ad + i * 2048 + ldst);
      async_copy16(B + boff[i] + k0, Bd + i * 2048 + ldst);
    }
  };

  const floatx4 zero = {0.f, 0.f, 0.f, 0.f};
  floatx4 acc[4][4];
#pragma unroll
  for (int i = 0; i < 4; ++i)
#pragma unroll
    for (int j = 0; j < 4; ++j) acc[i][j] = zero;

  const int slot = (quad ^ (l4 & 3) ^ ((l4 >> 2) & 1)) * 8;  // read swizzle

  stage(0, 0);
  for (int kt = 0; kt < 32; ++kt) {
    if (kt < 31) {
      stage((kt + 1) & 1, kt + 1);
      asm volatile("s_waitcnt vmcnt(4)" ::: "memory");  // t landed; t+1 flying
    } else {
      asm volatile("s_waitcnt vmcnt(0)" ::: "memory");
    }
    __builtin_amdgcn_s_barrier();
    const _Float16* As = smem + (kt & 1) * 8192;
    const _Float16* Bs = As + 4096;
    half8 af[4], bf[4];
#pragma unroll
    for (int mt = 0; mt < 4; ++mt)
      af[mt] = *(const half8*)(As + (wm * 64 + mt * 16 + l4) * 32 + slot);
#pragma unroll
    for (int nt = 0; nt < 4; ++nt)
      bf[nt] = *(const half8*)(Bs + (wn * 64 + nt * 16 + l4) * 32 + slot);
#pragma unroll
    for (int mt = 0; mt < 4; ++mt)
#pragma unroll
      for (int nt = 0; nt < 4; ++nt)
        acc[mt][nt] = __builtin_amdgcn_mfma_f32_16x16x32_f16(af[mt], bf[nt], acc[mt][nt], 0, 0, 0);
    // trailing: reads retired before anyone restages this buffer.
    asm volatile("s_waitcnt lgkmcnt(0)" ::: "memory");
    __builtin_amdgcn_sched_barrier(0);
    __builtin_amdgcn_s_barrier();
  }

  // epilogue: bias (+RoPE) in C-layout -> LDS tile -> coalesced half8 stores.
  // q,k: tile[m][n], store [bh][s][d]. V: tile[n][m], store V^T [bh][d][s].
  _Float16* tile = smem;                    // [128][132]
#pragma unroll
  for (int nt = 0; nt < 4; ++nt) {
    const int n = n0 + wn * 64 + nt * 16 + l4;
    const float bval = bias[n];
    const int hh = n >> 6;
    float c_ = 1.f, ss = 0.f;
    if (dorope) {
      const float freq = __expf((float)(n & 31) * -0.28782314f);  // ln(1e4)/32
      float s_;
      __sincosf((float)hh * freq, &s_, &c_);
      ss = (n & 1) ? s_ : -s_;
    }
#pragma unroll
    for (int mt = 0; mt < 4; ++mt)
#pragma unroll
      for (int r = 0; r < 4; ++r) {
        float val = acc[mt][nt][r] + bval;
        const float prt = __shfl_xor(val, 1);
        if (dorope) val = (val * c_ + prt * ss) * scl;
        const int ml = wm * 64 + mt * 16 + quad * 4 + r;
        const int nl = wn * 64 + nt * 16 + l4;
        if (z == 2) tile[nl * 132 + ml] = (_Float16)val;   // transposed
        else        tile[ml * 132 + nl] = (_Float16)val;
      }
  }
  __syncthreads();
  if (z == 2) {
#pragma unroll
    for (int j = 0; j < 8; ++j) {
      const int idx = j * 256 + tid;        // 128 d-rows x 16 s-chunks
      const int row = idx >> 4, cb = idx & 15;
      const int n = n0 + row, hh = n >> 6, dd = n & 63;
      const int m = m0 + cb * 8, bb = m >> 12, s = m & 4095;
      const half8 vals = *(const half8*)(tile + row * 132 + cb * 8);
      *(half8*)(out + (bb * 16 + hh) * 262144 + dd * 4096 + s) = vals;
    }
  } else {
#pragma unroll
    for (int j = 0; j < 8; ++j) {
      const int idx = j * 256 + tid;        // 128 s-rows x 16 d-chunks
      const int row = idx >> 4, cb = idx & 15;
      const int n = n0 + cb * 8, hh = n >> 6, dd = n & 63;
      const int m = m0 + row, bb = m >> 12, s = m & 4095;
      const half8 vals = *(const half8*)(tile + row * 132 + cb * 8);
      *(half8*)(out + ((bb * 16 + hh) * 4096 + s) * 64 + dd) = vals;
    }
  }
}

// ---------------------------------------------------------------- out GEMM
// R11: same BK=32 dbuf stage-ahead structure as gemm_qkv.
__global__ __launch_bounds__(256, 2) void gemm_out_kernel(
    const _Float16* __restrict__ A, const _Float16* __restrict__ B,
    const float* __restrict__ bias, float* __restrict__ out) {
  __shared__ _Float16 smem[16384];          // 2 bufs 2x8192

  const int tid = threadIdx.x;
  const int w = tid >> 6, lane = tid & 63;
  const int l4 = lane & 15, quad = lane >> 4;
  const int wm = w & 1, wn = w >> 1;

  const int bid = blockIdx.x;
  const int xcd = bid & 7, li = bid >> 3;   // li in 0..63
  const int n_l = li >> 3, m_l = li & 7;
  const int m0 = (xcd * 8 + m_l) * 128;
  const int n0 = n_l * 128;

  int aoff[2], boff[2];
#pragma unroll
  for (int i = 0; i < 2; ++i) {
    const int p = i * 256 + tid;
    const int r = p >> 2;
    const int c = (p & 3) ^ (r & 3) ^ ((r >> 2) & 1);
    aoff[i] = (m0 + r) * 1024 + c * 8;
    boff[i] = (n0 + r) * 1024 + c * 8;
  }
  const int ldst = w * 512;

  auto stage = [&](int b_, int kt) {
    _Float16* Ad = smem + b_ * 8192;
    _Float16* Bd = Ad + 4096;
    const int k0 = kt * 32;
#pragma unroll
    for (int i = 0; i < 2; ++i) {
      async_copy16(A + aoff[i] + k0, Ad + i * 2048 + ldst);
      async_copy16(B + boff[i] + k0, Bd + i * 2048 + ldst);
    }
  };

  const floatx4 zero = {0.f, 0.f, 0.f, 0.f};
  floatx4 acc[4][4];
#pragma unroll
  for (int i = 0; i < 4; ++i)
#pragma unroll
    for (int j = 0; j < 4; ++j) acc[i][j] = zero;

  const int slot = (quad ^ (l4 & 3) ^ ((l4 >> 2) & 1)) * 8;

  stage(0, 0);
  for (int kt = 0; kt < 32; ++kt) {
    if (kt < 31) {
      stage((kt + 1) & 1, kt + 1);
      asm volatile("s_waitcnt vmcnt(4)" ::: "memory");
    } else {
      asm volatile("s_waitcnt vmcnt(0)" ::: "memory");
    }
    __builtin_amdgcn_s_barrier();
    const _Float16* As = smem + (kt & 1) * 8192;
    const _Float16* Bs = As + 4096;
    half8 af[4], bf[4];
#pragma unroll
    for (int mt = 0; mt < 4; ++mt)
      af[mt] = *(const half8*)(As + (wm * 64 + mt * 16 + l4) * 32 + slot);
#pragma unroll
    for (int nt = 0; nt < 4; ++nt)
      bf[nt] = *(const half8*)(Bs + (wn * 64 + nt * 16 + l4) * 32 + slot);
#pragma unroll
    for (int mt = 0; mt < 4; ++mt)
#pragma unroll
      for (int nt = 0; nt < 4; ++nt)
        acc[mt][nt] = __builtin_amdgcn_mfma_f32_16x16x32_f16(af[mt], bf[nt], acc[mt][nt], 0, 0, 0);
    asm volatile("s_waitcnt lgkmcnt(0)" ::: "memory");
    __builtin_amdgcn_sched_barrier(0);
    __builtin_amdgcn_s_barrier();
  }

#pragma unroll
  for (int nt = 0; nt < 4; ++nt) {
    const int n = n0 + wn * 64 + nt * 16 + l4;
    const float bval = bias[n];
#pragma unroll
    for (int mt = 0; mt < 4; ++mt)
#pragma unroll
      for (int r = 0; r < 4; ++r) {
        const int m = m0 + wm * 64 + mt * 16 + quad * 4 + r;
        out[m * 1024 + n] = acc[mt][nt][r] + bval;
      }
  }
}

// ---------------------------------------------------------------- attention
// Unchanged from R10 (verified -27us win). S^T formulation; 256 q/block;
// double-buffered KV staging, stage-ahead + vmcnt(8); raw barriers; exact
// per-wave band skip/mask; XCD-grouped bh (4 heads/XCD, KV L2-fit).
__global__ __launch_bounds__(256, 2) void attn_kernel(
    const _Float16* __restrict__ qg, const _Float16* __restrict__ kg,
    const _Float16* __restrict__ vtg, _Float16* __restrict__ ctx) {
  __shared__ _Float16 Ks[2][128 * 64];   // [buf][key][d]
  __shared__ _Float16 Vs[2][64 * 128];   // [buf][d][key] (from vt)

  const int tid = threadIdx.x;
  const int w = tid >> 6, lane = tid & 63;
  const int l4 = lane & 15, quad = lane >> 4;

  const int bid = blockIdx.x;
  const int xcd = bid & 7, li = bid >> 3;   // li 0..63
  const int bh = xcd * 4 + (li >> 4);       // XCD owns 4 heads -> KV L2-fit
  const int q0 = (li & 15) * 256;

  const _Float16* qbh = qg + bh * 262144;
  const _Float16* kbh = kg + bh * 262144;
  const _Float16* vbh = vtg + bh * 262144;

  // Q as B-operand frags: query = q0 + sub*128 + w*32 + nt*16 + l4
  half8 qf[2][2][2];
#pragma unroll
  for (int sub = 0; sub < 2; ++sub)
#pragma unroll
    for (int nt = 0; nt < 2; ++nt)
#pragma unroll
      for (int ks = 0; ks < 2; ++ks)
        qf[sub][nt][ks] = *(const half8*)(qbh + (q0 + sub * 128 + w * 32 + nt * 16 + l4) * 64 +
                                          ks * 32 + quad * 8);

  const floatx4 zero = {0.f, 0.f, 0.f, 0.f};
  floatx4 OT[2][4][2];               // [sub][d-tile][q-tile]
  float l_st[2][2];                  // lane-local partial (this quad's keys)
#pragma unroll
  for (int sub = 0; sub < 2; ++sub) {
#pragma unroll
    for (int md = 0; md < 4; ++md)
#pragma unroll
      for (int nt = 0; nt < 2; ++nt) OT[sub][md][nt] = zero;
#pragma unroll
    for (int nt = 0; nt < 2; ++nt) l_st[sub][nt] = 0.f;
  }

  // valid kv-tile range: kv0(t) = q0 - 256 + t*128 in [0, 3968]
  const int tb = (q0 == 0) ? 2 : 0;
  const int te = (q0 == 3840) ? 3 : 5;

  // stage one 128-key tile (K + V^T slab) into buffer b_: 8 loads/thread.
  auto stage = [&](int b_, int kv0_) {
#pragma unroll
    for (int i = 0; i < 4; ++i) {
      const int p = i * 256 + tid;
      const int rk = p >> 3, ck = (p & 7) ^ (rk & 7);
      async_copy16(kbh + (kv0_ + rk) * 64 + ck * 8, &Ks[b_][(i * 256 + w * 64) * 8]);
      const int rv = p >> 4, cv = (p & 15) ^ (rv & 7);
      async_copy16(vbh + rv * 4096 + kv0_ + cv * 8, &Vs[b_][(i * 256 + w * 64) * 8]);
    }
  };

  stage(tb & 1, q0 - 256 + tb * 128);

  for (int t = tb; t <= te; ++t) {
    const int kv0 = q0 - 256 + t * 128;
    if (t < te) {
      stage((t + 1) & 1, kv0 + 128);
      asm volatile("s_waitcnt vmcnt(8)" ::: "memory");  // tile t landed; t+1 in flight
    } else {
      asm volatile("s_waitcnt vmcnt(0)" ::: "memory");  // last tile: drain
    }
    __builtin_amdgcn_s_barrier();
    const _Float16* Kc = Ks[t & 1];
    const _Float16* Vc = Vs[t & 1];

#pragma unroll
    for (int sub = 0; sub < 2; ++sub) {
      const int qbase = q0 + sub * 128 + w * 32;   // this wave's 32 queries
#pragma unroll
      for (int hf = 0; hf < 2; ++hf) {
        const int kb = hf * 64;
        const int k_lo = kv0 + kb, k_hi = k_lo + 63;
        // wave-uniform: all 64 keys outside band for all 32 queries -> skip
        if (k_lo - (qbase + 31) > 256 || k_hi - qbase < -256) continue;
        const bool needm = (k_lo - (qbase + 31) < -256) || (k_hi - qbase > 256);

        floatx4 ST[4][2];
#pragma unroll
        for (int m = 0; m < 4; ++m)
#pragma unroll
          for (int nt = 0; nt < 2; ++nt) ST[m][nt] = zero;
#pragma unroll
        for (int ks = 0; ks < 2; ++ks)
#pragma unroll
          for (int m = 0; m < 4; ++m) {
            const half8 kf = *(const half8*)(Kc + (kb + m * 16 + l4) * 64 +
                                             ((ks * 4 + quad) ^ (l4 & 7)) * 8);
#pragma unroll
            for (int nt = 0; nt < 2; ++nt)
              ST[m][nt] = __builtin_amdgcn_mfma_f32_16x16x32_f16(kf, qf[sub][nt][ks], ST[m][nt], 0, 0, 0);
          }

        if (needm) {  // band mask |key - query| <= 256
#pragma unroll
          for (int m = 0; m < 4; ++m)
#pragma unroll
            for (int r = 0; r < 4; ++r) {
              const int key = kv0 + kb + m * 16 + quad * 4 + r;
#pragma unroll
              for (int nt = 0; nt < 2; ++nt) {
                const int d = key - (qbase + nt * 16 + l4);
                if (d < -256 || d > 256) ST[m][nt][r] = -1e30f;
              }
            }
        }

        // P = exp2(S - 4); lane-local l accumulation (no max, no rescale)
#pragma unroll
        for (int nt = 0; nt < 2; ++nt) {
          float rs = 0.f;
#pragma unroll
          for (int m = 0; m < 4; ++m)
#pragma unroll
            for (int r = 0; r < 4; ++r) {
              const float pv = exp2f(ST[m][nt][r] - 4.0f);
              ST[m][nt][r] = pv;
              rs += pv;
            }
          l_st[sub][nt] += rs;
        }

        // O^T += V^T P^T; P B-frag = packed ST C-frag (k=quad*4+j)
#pragma unroll
        for (int m = 0; m < 4; ++m) {
          half4v pb[2];
#pragma unroll
          for (int nt = 0; nt < 2; ++nt) {
            const auto lo = __builtin_amdgcn_cvt_pkrtz(ST[m][nt][0], ST[m][nt][1]);
            const auto hi = __builtin_amdgcn_cvt_pkrtz(ST[m][nt][2], ST[m][nt][3]);
            pb[nt][0] = (_Float16)lo[0]; pb[nt][1] = (_Float16)lo[1];
            pb[nt][2] = (_Float16)hi[0]; pb[nt][3] = (_Float16)hi[1];
          }
#pragma unroll
          for (int md = 0; md < 4; ++md) {
            const half4v vf = *(const half4v*)(Vc + (md * 16 + l4) * 128 +
                                               (((hf * 8 + m * 2 + (quad >> 1)) ^ (l4 & 7)) * 8 +
                                                (quad & 1) * 4));
#pragma unroll
            for (int nt = 0; nt < 2; ++nt)
              OT[sub][md][nt] = __builtin_amdgcn_mfma_f32_16x16x16f16(vf, pb[nt], OT[sub][md][nt], 0, 0, 0);
          }
        }
      }
    }

    if (t < te) {
      // trailing barrier: my ds_reads of this buffer must retire before any
      // wave stages into it next iteration. NOT __syncthreads (vmcnt drain).
      asm volatile("s_waitcnt lgkmcnt(0)" ::: "memory");
      __builtin_amdgcn_sched_barrier(0);
      __builtin_amdgcn_s_barrier();
    }
  }

  // epilogue: reduce l across quads (keys were quad-distributed), then scale.
  const int b = bh >> 4, hh = bh & 15;
#pragma unroll
  for (int sub = 0; sub < 2; ++sub)
#pragma unroll
    for (int nt = 0; nt < 2; ++nt) {
      float lt = l_st[sub][nt];
      lt += __shfl_xor(lt, 16);
      lt += __shfl_xor(lt, 32);
      const float inv_l = 1.f / lt;
      const int s = q0 + sub * 128 + w * 32 + nt * 16 + l4;
#pragma unroll
      for (int md = 0; md < 4; ++md) {
        half4v o;
#pragma unroll
        for (int r = 0; r < 4; ++r) o[r] = (_Float16)(OT[sub][md][nt][r] * inv_l);
        *(half4v*)(ctx + (b * 4096 + s) * 1024 + hh * 64 + md * 16 + quad * 4) = o;
      }
    }
}

// ---------------------------------------------------------------- launch
extern "C" void kernel_launch(void* const* d_in, const int* in_sizes, int n_in,
                              void* d_out, int out_size, void* d_ws, size_t ws_size,
                              hipStream_t stream) {
  const float* x  = (const float*)d_in[0];
  const float* Wq = (const float*)d_in[1];
  const float* bq = (const float*)d_in[2];
  const float* Wk = (const float*)d_in[3];
  const float* bk = (const float*)d_in[4];
  const float* Wv = (const float*)d_in[5];
  const float* bv = (const float*)d_in[6];
  const float* Wo = (const float*)d_in[7];
  const float* bo = (const float*)d_in[8];

  _Float16* ws   = (_Float16*)d_ws;       // all offsets in halfs
  _Float16* xh   = ws;                    // 8388608
  _Float16* wqh  = ws + 8388608;          // 1048576 each
  _Float16* wkh  = ws + 9437184;
  _Float16* wvh  = ws + 10485760;
  _Float16* woh  = ws + 11534336;
  _Float16* qh   = ws + 12582912;         // [b,h,s,d] fp16, rope+scale applied
  _Float16* kh   = ws + 20971520;         // [b,h,s,d] fp16, rope applied
  _Float16* vth  = ws + 29360128;         // [b,h,d,s] fp16 (written directly)
  _Float16* ctxh = xh;                    // reuse: x dead after QKV GEMM

  convert_kernel<<<12288, 256, 0, stream>>>(x, Wq, Wk, Wv, Wo, ws);
  gemm_qkv_kernel<<<1536, 256, 0, stream>>>(xh, wqh, wkh, wvh,
                                            bq, bk, bv, qh, kh, vth);
  attn_kernel<<<512, 256, 0, stream>>>(qh, kh, vth, ctxh);
  gemm_out_kernel<<<512, 256, 0, stream>>>(ctxh, woh, bo, (float*)d_out);
}

// Round 5
// 233.868 us; speedup vs baseline: 1.0097x; 1.0097x over previous
//
#include <hip/hip_runtime.h>

// LongformerAttention on MI355X (gfx950), fp16 MFMA pipeline, round 12.
// R12: R11 post-mortem - BK=32 swizzle caused 25x bank conflicts (6.5M) and
// MfmaUtil 33->29. Revised: keep R7's PROVEN LDS geometry byte-for-byte
// (BK=64, 128B rows, chunk=(ks*4+quad)^(l4&7), measured 262K conflicts) and
// double-buffer THAT: 2x32KB LDS (2 blocks/CU - the co-residency at which
// R10's attn won with this same pattern). Per K-tile: stage(t+1) -> counted
// s_waitcnt vmcnt(8) (tile t's loads issued a full tile earlier -> near-zero
// wait) -> s_barrier -> 16 ds_read + 32 MFMA -> lgkmcnt(0) -> s_barrier.
// Barrier count unchanged vs R7 (32); only the vmcnt(0)-drain-at-issue (the
// m97 stall that capped MfmaUtil at 33%) is removed.
// Attn/convert unchanged from R10 (verified -27us win, control).

typedef _Float16 half8 __attribute__((ext_vector_type(8)));
typedef _Float16 half4v __attribute__((ext_vector_type(4)));
typedef float floatx4 __attribute__((ext_vector_type(4)));

typedef __attribute__((address_space(3))) unsigned int lds_u32;
typedef const __attribute__((address_space(1))) unsigned int glb_u32;

__device__ __forceinline__ void async_copy16(const void* g, void* l) {
  // global -> LDS direct, 16 B/lane. LDS dest = wave-uniform base + lane*16.
  __builtin_amdgcn_global_load_lds((glb_u32*)g, (lds_u32*)l, 16, 0, 0);
}

// ---------------------------------------------------------------- convert
__global__ __launch_bounds__(256) void convert_kernel(
    const float* __restrict__ x, const float* __restrict__ wq,
    const float* __restrict__ wk, const float* __restrict__ wv,
    const float* __restrict__ wo, _Float16* __restrict__ dst) {
  const int e0 = (blockIdx.x * 256 + threadIdx.x) * 4;
  const float* src; int off;
  if      (e0 <  8388608) { src = x;  off = e0; }
  else if (e0 <  9437184) { src = wq; off = e0 -  8388608; }
  else if (e0 < 10485760) { src = wk; off = e0 -  9437184; }
  else if (e0 < 11534336) { src = wv; off = e0 - 10485760; }
  else                    { src = wo; off = e0 - 11534336; }
  const float4 f = *(const float4*)(src + off);
  half4v h;
  h[0] = (_Float16)f.x; h[1] = (_Float16)f.y;
  h[2] = (_Float16)f.z; h[3] = (_Float16)f.w;
  *(half4v*)(dst + e0) = h;
}

// ---------------------------------------------------------------- QKV GEMM
// out[m,n] = sum_k A[m,k]*W[n,k] + bias[n]; RoPE fused in epilogue for q,k
// (pair (n,n^1) in adjacent l4 lanes -> __shfl_xor(val,1)); q scaled log2e/8.
// z==2 (V): epilogue LDS tile stored transposed, output written as V^T
// [bh][d][s] directly.
// R12 main loop: BK=64 R7 geometry, double-buffered (2x32KB), stage-ahead
// + counted vmcnt(8), raw barriers (no vmcnt(0) drain in hot loop).
__global__ __launch_bounds__(256, 2) void gemm_qkv_kernel(
    const _Float16* __restrict__ A, const _Float16* __restrict__ w0,
    const _Float16* __restrict__ w1, const _Float16* __restrict__ w2,
    const float* __restrict__ b0, const float* __restrict__ b1,
    const float* __restrict__ b2, _Float16* __restrict__ o0,
    _Float16* __restrict__ o1, _Float16* __restrict__ o2) {
  __shared__ _Float16 smem[32768];          // 2 bufs x (A 8192 + B 8192)

  const int tid = threadIdx.x;
  const int w = tid >> 6, lane = tid & 63;
  const int l4 = lane & 15, quad = lane >> 4;
  const int wm = w & 1, wn = w >> 1;

  const int bid = blockIdx.x;
  const int xcd = bid & 7, li = bid >> 3;   // li in 0..191
  const int z = li >> 6, r_ = li & 63;
  const int n_l = r_ >> 3, m_l = r_ & 7;
  const int m0 = (xcd * 8 + m_l) * 128;
  const int n0 = n_l * 128;

  const _Float16* B; const float* bias; _Float16* out;
  if (z == 0)      { B = w0; bias = b0; out = o0; }
  else if (z == 1) { B = w1; bias = b1; out = o1; }
  else             { B = w2; bias = b2; out = o2; }
  const bool dorope = z < 2;
  const float scl = (z == 0) ? 0.18033688f : 1.0f;  // log2e/8

  // R7 staging map: p = i*256+tid, row r = p>>3, phys chunk c = (p&7)^(r&7).
  int aoff[4], boff[4];
#pragma unroll
  for (int i = 0; i < 4; ++i) {
    const int p = i * 256 + tid;
    const int r = p >> 3;
    const int c = (p & 7) ^ (r & 7);
    aoff[i] = (m0 + r) * 1024 + c * 8;
    boff[i] = (n0 + r) * 1024 + c * 8;
  }
  const int ldst = (w * 64) * 8;            // wave-uniform dest base (halfs)

  auto stage = [&](int b_, int kt) {        // 8 loads/thread: A(4) + B(4)
    _Float16* Ad = smem + b_ * 16384;
    _Float16* Bd = Ad + 8192;
    const int k0 = kt * 64;
#pragma unroll
    for (int i = 0; i < 4; ++i) {
      async_copy16(A + aoff[i] + k0, Ad + i * 2048 + ldst);
      async_copy16(B + boff[i] + k0, Bd + i * 2048 + ldst);
    }
  };

  const floatx4 zero = {0.f, 0.f, 0.f, 0.f};
  floatx4 acc[4][4];
#pragma unroll
  for (int i = 0; i < 4; ++i)
#pragma unroll
    for (int j = 0; j < 4; ++j) acc[i][j] = zero;

  stage(0, 0);
  for (int kt = 0; kt < 16; ++kt) {
    if (kt < 15) {
      stage((kt + 1) & 1, kt + 1);
      asm volatile("s_waitcnt vmcnt(8)" ::: "memory");  // tile kt landed; kt+1 flying
    } else {
      asm volatile("s_waitcnt vmcnt(0)" ::: "memory");
    }
    __builtin_amdgcn_s_barrier();
    const _Float16* As = smem + (kt & 1) * 16384;
    const _Float16* Bs = As + 8192;
#pragma unroll
    for (int ks = 0; ks < 2; ++ks) {
      half8 af[4], bf[4];
#pragma unroll
      for (int mt = 0; mt < 4; ++mt)
        af[mt] = *(const half8*)(As + (wm * 64 + mt * 16 + l4) * 64 +
                                 (((ks * 4 + quad) ^ (l4 & 7)) * 8));
#pragma unroll
      for (int nt = 0; nt < 4; ++nt)
        bf[nt] = *(const half8*)(Bs + (wn * 64 + nt * 16 + l4) * 64 +
                                 (((ks * 4 + quad) ^ (l4 & 7)) * 8));
#pragma unroll
      for (int mt = 0; mt < 4; ++mt)
#pragma unroll
        for (int nt = 0; nt < 4; ++nt)
          acc[mt][nt] = __builtin_amdgcn_mfma_f32_16x16x32_f16(af[mt], bf[nt], acc[mt][nt], 0, 0, 0);
    }
    // reads of this buffer retired before anyone restages it (kt+2 -> same buf)
    asm volatile("s_waitcnt lgkmcnt(0)" ::: "memory");
    __builtin_amdgcn_sched_barrier(0);
    __builtin_amdgcn_s_barrier();
  }

  // epilogue: bias (+RoPE) in C-layout -> LDS tile -> coalesced half8 stores.
  // q,k: tile[m][n], store [bh][s][d]. V: tile[n][m], store V^T [bh][d][s].
  _Float16* tile = smem;                    // [128][132]
#pragma unroll
  for (int nt = 0; nt < 4; ++nt) {
    const int n = n0 + wn * 64 + nt * 16 + l4;
    const float bval = bias[n];
    const int hh = n >> 6;
    float c_ = 1.f, ss = 0.f;
    if (dorope) {
      const float freq = __expf((float)(n & 31) * -0.28782314f);  // ln(1e4)/32
      float s_;
      __sincosf((float)hh * freq, &s_, &c_);
      ss = (n & 1) ? s_ : -s_;
    }
#pragma unroll
    for (int mt = 0; mt < 4; ++mt)
#pragma unroll
      for (int r = 0; r < 4; ++r) {
        float val = acc[mt][nt][r] + bval;
        const float prt = __shfl_xor(val, 1);
        if (dorope) val = (val * c_ + prt * ss) * scl;
        const int ml = wm * 64 + mt * 16 + quad * 4 + r;
        const int nl = wn * 64 + nt * 16 + l4;
        if (z == 2) tile[nl * 132 + ml] = (_Float16)val;   // transposed
        else        tile[ml * 132 + nl] = (_Float16)val;
      }
  }
  __syncthreads();
  if (z == 2) {
#pragma unroll
    for (int j = 0; j < 8; ++j) {
      const int idx = j * 256 + tid;        // 128 d-rows x 16 s-chunks
      const int row = idx >> 4, cb = idx & 15;
      const int n = n0 + row, hh = n >> 6, dd = n & 63;
      const int m = m0 + cb * 8, bb = m >> 12, s = m & 4095;
      const half8 vals = *(const half8*)(tile + row * 132 + cb * 8);
      *(half8*)(out + (bb * 16 + hh) * 262144 + dd * 4096 + s) = vals;
    }
  } else {
#pragma unroll
    for (int j = 0; j < 8; ++j) {
      const int idx = j * 256 + tid;        // 128 s-rows x 16 d-chunks
      const int row = idx >> 4, cb = idx & 15;
      const int n = n0 + cb * 8, hh = n >> 6, dd = n & 63;
      const int m = m0 + row, bb = m >> 12, s = m & 4095;
      const half8 vals = *(const half8*)(tile + row * 132 + cb * 8);
      *(half8*)(out + ((bb * 16 + hh) * 4096 + s) * 64 + dd) = vals;
    }
  }
}

// ---------------------------------------------------------------- out GEMM
// R12: same BK=64 dbuf stage-ahead structure as gemm_qkv.
__global__ __launch_bounds__(256, 2) void gemm_out_kernel(
    const _Float16* __restrict__ A, const _Float16* __restrict__ B,
    const float* __restrict__ bias, float* __restrict__ out) {
  __shared__ _Float16 smem[32768];          // 2 bufs x (A 8192 + B 8192)

  const int tid = threadIdx.x;
  const int w = tid >> 6, lane = tid & 63;
  const int l4 = lane & 15, quad = lane >> 4;
  const int wm = w & 1, wn = w >> 1;

  const int bid = blockIdx.x;
  const int xcd = bid & 7, li = bid >> 3;   // li in 0..63
  const int n_l = li >> 3, m_l = li & 7;
  const int m0 = (xcd * 8 + m_l) * 128;
  const int n0 = n_l * 128;

  int aoff[4], boff[4];
#pragma unroll
  for (int i = 0; i < 4; ++i) {
    const int p = i * 256 + tid;
    const int r = p >> 3;
    const int c = (p & 7) ^ (r & 7);
    aoff[i] = (m0 + r) * 1024 + c * 8;
    boff[i] = (n0 + r) * 1024 + c * 8;
  }
  const int ldst = (w * 64) * 8;

  auto stage = [&](int b_, int kt) {
    _Float16* Ad = smem + b_ * 16384;
    _Float16* Bd = Ad + 8192;
    const int k0 = kt * 64;
#pragma unroll
    for (int i = 0; i < 4; ++i) {
      async_copy16(A + aoff[i] + k0, Ad + i * 2048 + ldst);
      async_copy16(B + boff[i] + k0, Bd + i * 2048 + ldst);
    }
  };

  const floatx4 zero = {0.f, 0.f, 0.f, 0.f};
  floatx4 acc[4][4];
#pragma unroll
  for (int i = 0; i < 4; ++i)
#pragma unroll
    for (int j = 0; j < 4; ++j) acc[i][j] = zero;

  stage(0, 0);
  for (int kt = 0; kt < 16; ++kt) {
    if (kt < 15) {
      stage((kt + 1) & 1, kt + 1);
      asm volatile("s_waitcnt vmcnt(8)" ::: "memory");
    } else {
      asm volatile("s_waitcnt vmcnt(0)" ::: "memory");
    }
    __builtin_amdgcn_s_barrier();
    const _Float16* As = smem + (kt & 1) * 16384;
    const _Float16* Bs = As + 8192;
#pragma unroll
    for (int ks = 0; ks < 2; ++ks) {
      half8 af[4], bf[4];
#pragma unroll
      for (int mt = 0; mt < 4; ++mt)
        af[mt] = *(const half8*)(As + (wm * 64 + mt * 16 + l4) * 64 +
                                 (((ks * 4 + quad) ^ (l4 & 7)) * 8));
#pragma unroll
      for (int nt = 0; nt < 4; ++nt)
        bf[nt] = *(const half8*)(Bs + (wn * 64 + nt * 16 + l4) * 64 +
                                 (((ks * 4 + quad) ^ (l4 & 7)) * 8));
#pragma unroll
      for (int mt = 0; mt < 4; ++mt)
#pragma unroll
        for (int nt = 0; nt < 4; ++nt)
          acc[mt][nt] = __builtin_amdgcn_mfma_f32_16x16x32_f16(af[mt], bf[nt], acc[mt][nt], 0, 0, 0);
    }
    asm volatile("s_waitcnt lgkmcnt(0)" ::: "memory");
    __builtin_amdgcn_sched_barrier(0);
    __builtin_amdgcn_s_barrier();
  }

#pragma unroll
  for (int nt = 0; nt < 4; ++nt) {
    const int n = n0 + wn * 64 + nt * 16 + l4;
    const float bval = bias[n];
#pragma unroll
    for (int mt = 0; mt < 4; ++mt)
#pragma unroll
      for (int r = 0; r < 4; ++r) {
        const int m = m0 + wm * 64 + mt * 16 + quad * 4 + r;
        out[m * 1024 + n] = acc[mt][nt][r] + bval;
      }
  }
}

// ---------------------------------------------------------------- attention
// Unchanged from R10 (verified -27us win). S^T formulation; 256 q/block;
// double-buffered KV staging, stage-ahead + vmcnt(8); raw barriers; exact
// per-wave band skip/mask; XCD-grouped bh (4 heads/XCD, KV L2-fit).
__global__ __launch_bounds__(256, 2) void attn_kernel(
    const _Float16* __restrict__ qg, const _Float16* __restrict__ kg,
    const _Float16* __restrict__ vtg, _Float16* __restrict__ ctx) {
  __shared__ _Float16 Ks[2][128 * 64];   // [buf][key][d]
  __shared__ _Float16 Vs[2][64 * 128];   // [buf][d][key] (from vt)

  const int tid = threadIdx.x;
  const int w = tid >> 6, lane = tid & 63;
  const int l4 = lane & 15, quad = lane >> 4;

  const int bid = blockIdx.x;
  const int xcd = bid & 7, li = bid >> 3;   // li 0..63
  const int bh = xcd * 4 + (li >> 4);       // XCD owns 4 heads -> KV L2-fit
  const int q0 = (li & 15) * 256;

  const _Float16* qbh = qg + bh * 262144;
  const _Float16* kbh = kg + bh * 262144;
  const _Float16* vbh = vtg + bh * 262144;

  // Q as B-operand frags: query = q0 + sub*128 + w*32 + nt*16 + l4
  half8 qf[2][2][2];
#pragma unroll
  for (int sub = 0; sub < 2; ++sub)
#pragma unroll
    for (int nt = 0; nt < 2; ++nt)
#pragma unroll
      for (int ks = 0; ks < 2; ++ks)
        qf[sub][nt][ks] = *(const half8*)(qbh + (q0 + sub * 128 + w * 32 + nt * 16 + l4) * 64 +
                                          ks * 32 + quad * 8);

  const floatx4 zero = {0.f, 0.f, 0.f, 0.f};
  floatx4 OT[2][4][2];               // [sub][d-tile][q-tile]
  float l_st[2][2];                  // lane-local partial (this quad's keys)
#pragma unroll
  for (int sub = 0; sub < 2; ++sub) {
#pragma unroll
    for (int md = 0; md < 4; ++md)
#pragma unroll
      for (int nt = 0; nt < 2; ++nt) OT[sub][md][nt] = zero;
#pragma unroll
    for (int nt = 0; nt < 2; ++nt) l_st[sub][nt] = 0.f;
  }

  // valid kv-tile range: kv0(t) = q0 - 256 + t*128 in [0, 3968]
  const int tb = (q0 == 0) ? 2 : 0;
  const int te = (q0 == 3840) ? 3 : 5;

  // stage one 128-key tile (K + V^T slab) into buffer b_: 8 loads/thread.
  auto stage = [&](int b_, int kv0_) {
#pragma unroll
    for (int i = 0; i < 4; ++i) {
      const int p = i * 256 + tid;
      const int rk = p >> 3, ck = (p & 7) ^ (rk & 7);
      async_copy16(kbh + (kv0_ + rk) * 64 + ck * 8, &Ks[b_][(i * 256 + w * 64) * 8]);
      const int rv = p >> 4, cv = (p & 15) ^ (rv & 7);
      async_copy16(vbh + rv * 4096 + kv0_ + cv * 8, &Vs[b_][(i * 256 + w * 64) * 8]);
    }
  };

  stage(tb & 1, q0 - 256 + tb * 128);

  for (int t = tb; t <= te; ++t) {
    const int kv0 = q0 - 256 + t * 128;
    if (t < te) {
      stage((t + 1) & 1, kv0 + 128);
      asm volatile("s_waitcnt vmcnt(8)" ::: "memory");  // tile t landed; t+1 in flight
    } else {
      asm volatile("s_waitcnt vmcnt(0)" ::: "memory");  // last tile: drain
    }
    __builtin_amdgcn_s_barrier();
    const _Float16* Kc = Ks[t & 1];
    const _Float16* Vc = Vs[t & 1];

#pragma unroll
    for (int sub = 0; sub < 2; ++sub) {
      const int qbase = q0 + sub * 128 + w * 32;   // this wave's 32 queries
#pragma unroll
      for (int hf = 0; hf < 2; ++hf) {
        const int kb = hf * 64;
        const int k_lo = kv0 + kb, k_hi = k_lo + 63;
        // wave-uniform: all 64 keys outside band for all 32 queries -> skip
        if (k_lo - (qbase + 31) > 256 || k_hi - qbase < -256) continue;
        const bool needm = (k_lo - (qbase + 31) < -256) || (k_hi - qbase > 256);

        floatx4 ST[4][2];
#pragma unroll
        for (int m = 0; m < 4; ++m)
#pragma unroll
          for (int nt = 0; nt < 2; ++nt) ST[m][nt] = zero;
#pragma unroll
        for (int ks = 0; ks < 2; ++ks)
#pragma unroll
          for (int m = 0; m < 4; ++m) {
            const half8 kf = *(const half8*)(Kc + (kb + m * 16 + l4) * 64 +
                                             ((ks * 4 + quad) ^ (l4 & 7)) * 8);
#pragma unroll
            for (int nt = 0; nt < 2; ++nt)
              ST[m][nt] = __builtin_amdgcn_mfma_f32_16x16x32_f16(kf, qf[sub][nt][ks], ST[m][nt], 0, 0, 0);
          }

        if (needm) {  // band mask |key - query| <= 256
#pragma unroll
          for (int m = 0; m < 4; ++m)
#pragma unroll
            for (int r = 0; r < 4; ++r) {
              const int key = kv0 + kb + m * 16 + quad * 4 + r;
#pragma unroll
              for (int nt = 0; nt < 2; ++nt) {
                const int d = key - (qbase + nt * 16 + l4);
                if (d < -256 || d > 256) ST[m][nt][r] = -1e30f;
              }
            }
        }

        // P = exp2(S - 4); lane-local l accumulation (no max, no rescale)
#pragma unroll
        for (int nt = 0; nt < 2; ++nt) {
          float rs = 0.f;
#pragma unroll
          for (int m = 0; m < 4; ++m)
#pragma unroll
            for (int r = 0; r < 4; ++r) {
              const float pv = exp2f(ST[m][nt][r] - 4.0f);
              ST[m][nt][r] = pv;
              rs += pv;
            }
          l_st[sub][nt] += rs;
        }

        // O^T += V^T P^T; P B-frag = packed ST C-frag (k=quad*4+j)
#pragma unroll
        for (int m = 0; m < 4; ++m) {
          half4v pb[2];
#pragma unroll
          for (int nt = 0; nt < 2; ++nt) {
            const auto lo = __builtin_amdgcn_cvt_pkrtz(ST[m][nt][0], ST[m][nt][1]);
            const auto hi = __builtin_amdgcn_cvt_pkrtz(ST[m][nt][2], ST[m][nt][3]);
            pb[nt][0] = (_Float16)lo[0]; pb[nt][1] = (_Float16)lo[1];
            pb[nt][2] = (_Float16)hi[0]; pb[nt][3] = (_Float16)hi[1];
          }
#pragma unroll
          for (int md = 0; md < 4; ++md) {
            const half4v vf = *(const half4v*)(Vc + (md * 16 + l4) * 128 +
                                               (((hf * 8 + m * 2 + (quad >> 1)) ^ (l4 & 7)) * 8 +
                                                (quad & 1) * 4));
#pragma unroll
            for (int nt = 0; nt < 2; ++nt)
              OT[sub][md][nt] = __builtin_amdgcn_mfma_f32_16x16x16f16(vf, pb[nt], OT[sub][md][nt], 0, 0, 0);
          }
        }
      }
    }

    if (t < te) {
      // trailing barrier: my ds_reads of this buffer must retire before any
      // wave stages into it next iteration. NOT __syncthreads (vmcnt drain).
      asm volatile("s_waitcnt lgkmcnt(0)" ::: "memory");
      __builtin_amdgcn_sched_barrier(0);
      __builtin_amdgcn_s_barrier();
    }
  }

  // epilogue: reduce l across quads (keys were quad-distributed), then scale.
  const int b = bh >> 4, hh = bh & 15;
#pragma unroll
  for (int sub = 0; sub < 2; ++sub)
#pragma unroll
    for (int nt = 0; nt < 2; ++nt) {
      float lt = l_st[sub][nt];
      lt += __shfl_xor(lt, 16);
      lt += __shfl_xor(lt, 32);
      const float inv_l = 1.f / lt;
      const int s = q0 + sub * 128 + w * 32 + nt * 16 + l4;
#pragma unroll
      for (int md = 0; md < 4; ++md) {
        half4v o;
#pragma unroll
        for (int r = 0; r < 4; ++r) o[r] = (_Float16)(OT[sub][md][nt][r] * inv_l);
        *(half4v*)(ctx + (b * 4096 + s) * 1024 + hh * 64 + md * 16 + quad * 4) = o;
      }
    }
}

// ---------------------------------------------------------------- launch
extern "C" void kernel_launch(void* const* d_in, const int* in_sizes, int n_in,
                              void* d_out, int out_size, void* d_ws, size_t ws_size,
                              hipStream_t stream) {
  const float* x  = (const float*)d_in[0];
  const float* Wq = (const float*)d_in[1];
  const float* bq = (const float*)d_in[2];
  const float* Wk = (const float*)d_in[3];
  const float* bk = (const float*)d_in[4];
  const float* Wv = (const float*)d_in[5];
  const float* bv = (const float*)d_in[6];
  const float* Wo = (const float*)d_in[7];
  const float* bo = (const float*)d_in[8];

  _Float16* ws   = (_Float16*)d_ws;       // all offsets in halfs
  _Float16* xh   = ws;                    // 8388608
  _Float16* wqh  = ws + 8388608;          // 1048576 each
  _Float16* wkh  = ws + 9437184;
  _Float16* wvh  = ws + 10485760;
  _Float16* woh  = ws + 11534336;
  _Float16* qh   = ws + 12582912;         // [b,h,s,d] fp16, rope+scale applied
  _Float16* kh   = ws + 20971520;         // [b,h,s,d] fp16, rope applied
  _Float16* vth  = ws + 29360128;         // [b,h,d,s] fp16 (written directly)
  _Float16* ctxh = xh;                    // reuse: x dead after QKV GEMM

  convert_kernel<<<12288, 256, 0, stream>>>(x, Wq, Wk, Wv, Wo, ws);
  gemm_qkv_kernel<<<1536, 256, 0, stream>>>(xh, wqh, wkh, wvh,
                                            bq, bk, bv, qh, kh, vth);
  attn_kernel<<<512, 256, 0, stream>>>(qh, kh, vth, ctxh);
  gemm_out_kernel<<<512, 256, 0, stream>>>(ctxh, woh, bo, (float*)d_out);
}

// Round 6
// 230.869 us; speedup vs baseline: 1.0228x; 1.0130x over previous
//
#include <hip/hip_runtime.h>

// LongformerAttention on MI355X (gfx950), fp16 MFMA pipeline, round 13.
// R13: GEMM-restructure arc closed. R12's discriminating test resolved:
// dbuf at 2 blocks/CU loses to R7's 4-block implicit overlap (MfmaUtil
// 33->23.7). Both GEMMs back to the PROVEN R7 single-buffer structure.
// This round's changes, both inside proven structures:
//   - gemm_out: 128x64 tiles -> grid 1024 = exactly 4 blocks/CU (was 512 =
//     2/CU, the one GEMM where TLP binds). LDS 24.5 KB, acc[4][2]/wave,
//     B-tile keeps the proven 128B-row + chunk-swizzle geometry verbatim.
//   - attn: s_setprio(1)/(0) around the QK MFMA cluster and the PV
//     pack+MFMA cluster (T5: +4-7% attn, A/B-verified; independent blocks
//     at different phases = the mechanism's regime).
// qkv/convert/attn-structure unchanged from R10 (best measured, 226.0 us).

typedef _Float16 half8 __attribute__((ext_vector_type(8)));
typedef _Float16 half4v __attribute__((ext_vector_type(4)));
typedef float floatx4 __attribute__((ext_vector_type(4)));

typedef __attribute__((address_space(3))) unsigned int lds_u32;
typedef const __attribute__((address_space(1))) unsigned int glb_u32;

__device__ __forceinline__ void async_copy16(const void* g, void* l) {
  // global -> LDS direct, 16 B/lane. LDS dest = wave-uniform base + lane*16.
  __builtin_amdgcn_global_load_lds((glb_u32*)g, (lds_u32*)l, 16, 0, 0);
}

// ---------------------------------------------------------------- convert
__global__ __launch_bounds__(256) void convert_kernel(
    const float* __restrict__ x, const float* __restrict__ wq,
    const float* __restrict__ wk, const float* __restrict__ wv,
    const float* __restrict__ wo, _Float16* __restrict__ dst) {
  const int e0 = (blockIdx.x * 256 + threadIdx.x) * 4;
  const float* src; int off;
  if      (e0 <  8388608) { src = x;  off = e0; }
  else if (e0 <  9437184) { src = wq; off = e0 -  8388608; }
  else if (e0 < 10485760) { src = wk; off = e0 -  9437184; }
  else if (e0 < 11534336) { src = wv; off = e0 - 10485760; }
  else                    { src = wo; off = e0 - 11534336; }
  const float4 f = *(const float4*)(src + off);
  half4v h;
  h[0] = (_Float16)f.x; h[1] = (_Float16)f.y;
  h[2] = (_Float16)f.z; h[3] = (_Float16)f.w;
  *(half4v*)(dst + e0) = h;
}

// ---------------------------------------------------------------- QKV GEMM
// R7 structure (proven: MfmaUtil 33%, 262K conflicts = epilogue-only).
// out[m,n] = sum_k A[m,k]*W[n,k] + bias[n]; RoPE fused in epilogue for q,k
// (pair (n,n^1) in adjacent l4 lanes -> __shfl_xor(val,1)); q scaled log2e/8.
// z==2 (V): epilogue LDS tile stored transposed, output written as V^T
// [bh][d][s] directly.
__global__ __launch_bounds__(256, 2) void gemm_qkv_kernel(
    const _Float16* __restrict__ A, const _Float16* __restrict__ w0,
    const _Float16* __restrict__ w1, const _Float16* __restrict__ w2,
    const float* __restrict__ b0, const float* __restrict__ b1,
    const float* __restrict__ b2, _Float16* __restrict__ o0,
    _Float16* __restrict__ o1, _Float16* __restrict__ o2) {
  __shared__ _Float16 smem[17408];          // staging 32 KB / epi tile 33.8 KB
  _Float16* As = smem;                      // [128][64] chunk-swizzled
  _Float16* Bs = smem + 8192;

  const int tid = threadIdx.x;
  const int w = tid >> 6, lane = tid & 63;
  const int l4 = lane & 15, quad = lane >> 4;
  const int wm = w & 1, wn = w >> 1;

  const int bid = blockIdx.x;
  const int xcd = bid & 7, li = bid >> 3;   // li in 0..191
  const int z = li >> 6, r_ = li & 63;
  const int n_l = r_ >> 3, m_l = r_ & 7;
  const int m0 = (xcd * 8 + m_l) * 128;
  const int n0 = n_l * 128;

  const _Float16* B; const float* bias; _Float16* out;
  if (z == 0)      { B = w0; bias = b0; out = o0; }
  else if (z == 1) { B = w1; bias = b1; out = o1; }
  else             { B = w2; bias = b2; out = o2; }
  const bool dorope = z < 2;
  const float scl = (z == 0) ? 0.18033688f : 1.0f;  // log2e/8

  const floatx4 zero = {0.f, 0.f, 0.f, 0.f};
  floatx4 acc[4][4];
#pragma unroll
  for (int i = 0; i < 4; ++i)
#pragma unroll
    for (int j = 0; j < 4; ++j) acc[i][j] = zero;

  for (int kt = 0; kt < 16; ++kt) {
    const int k0 = kt * 64;
#pragma unroll
    for (int i = 0; i < 4; ++i) {
      const int p = i * 256 + tid;          // 128 rows x 8 chunks
      const int r = p >> 3;
      const int c = (p & 7) ^ (r & 7);      // 3-bit XOR chunk swizzle
      async_copy16(A + (m0 + r) * 1024 + k0 + c * 8, As + (i * 256 + w * 64) * 8);
      async_copy16(B + (n0 + r) * 1024 + k0 + c * 8, Bs + (i * 256 + w * 64) * 8);
    }
    __syncthreads();
#pragma unroll
    for (int ks = 0; ks < 2; ++ks) {
      half8 af[4], bf[4];
#pragma unroll
      for (int mt = 0; mt < 4; ++mt)
        af[mt] = *(const half8*)(As + (wm * 64 + mt * 16 + l4) * 64 +
                                 (((ks * 4 + quad) ^ (l4 & 7)) * 8));
#pragma unroll
      for (int nt = 0; nt < 4; ++nt)
        bf[nt] = *(const half8*)(Bs + (wn * 64 + nt * 16 + l4) * 64 +
                                 (((ks * 4 + quad) ^ (l4 & 7)) * 8));
#pragma unroll
      for (int mt = 0; mt < 4; ++mt)
#pragma unroll
        for (int nt = 0; nt < 4; ++nt)
          acc[mt][nt] = __builtin_amdgcn_mfma_f32_16x16x32_f16(af[mt], bf[nt], acc[mt][nt], 0, 0, 0);
    }
    __syncthreads();
  }

  // epilogue: bias (+RoPE) in C-layout -> LDS tile -> coalesced half8 stores.
  // q,k: tile[m][n], store [bh][s][d]. V: tile[n][m], store V^T [bh][d][s].
  _Float16* tile = smem;                    // [128][132]
#pragma unroll
  for (int nt = 0; nt < 4; ++nt) {
    const int n = n0 + wn * 64 + nt * 16 + l4;
    const float bval = bias[n];
    const int hh = n >> 6;
    float c_ = 1.f, ss = 0.f;
    if (dorope) {
      const float freq = __expf((float)(n & 31) * -0.28782314f);  // ln(1e4)/32
      float s_;
      __sincosf((float)hh * freq, &s_, &c_);
      ss = (n & 1) ? s_ : -s_;
    }
#pragma unroll
    for (int mt = 0; mt < 4; ++mt)
#pragma unroll
      for (int r = 0; r < 4; ++r) {
        float val = acc[mt][nt][r] + bval;
        const float prt = __shfl_xor(val, 1);
        if (dorope) val = (val * c_ + prt * ss) * scl;
        const int ml = wm * 64 + mt * 16 + quad * 4 + r;
        const int nl = wn * 64 + nt * 16 + l4;
        if (z == 2) tile[nl * 132 + ml] = (_Float16)val;   // transposed
        else        tile[ml * 132 + nl] = (_Float16)val;
      }
  }
  __syncthreads();
  if (z == 2) {
#pragma unroll
    for (int j = 0; j < 8; ++j) {
      const int idx = j * 256 + tid;        // 128 d-rows x 16 s-chunks
      const int row = idx >> 4, cb = idx & 15;
      const int n = n0 + row, hh = n >> 6, dd = n & 63;
      const int m = m0 + cb * 8, bb = m >> 12, s = m & 4095;
      const half8 vals = *(const half8*)(tile + row * 132 + cb * 8);
      *(half8*)(out + (bb * 16 + hh) * 262144 + dd * 4096 + s) = vals;
    }
  } else {
#pragma unroll
    for (int j = 0; j < 8; ++j) {
      const int idx = j * 256 + tid;        // 128 s-rows x 16 d-chunks
      const int row = idx >> 4, cb = idx & 15;
      const int n = n0 + cb * 8, hh = n >> 6, dd = n & 63;
      const int m = m0 + row, bb = m >> 12, s = m & 4095;
      const half8 vals = *(const half8*)(tile + row * 132 + cb * 8);
      *(half8*)(out + ((bb * 16 + hh) * 4096 + s) * 64 + dd) = vals;
    }
  }
}

// ---------------------------------------------------------------- out GEMM
// R13: 128x64 tiles -> 1024 blocks = 4 blocks/CU (was 2/CU; TLP-bound).
// Same R7 single-buffer structure; B-tile 64 rows, proven 128B-row swizzle.
__global__ __launch_bounds__(256, 2) void gemm_out_kernel(
    const _Float16* __restrict__ A, const _Float16* __restrict__ B,
    const float* __restrict__ bias, float* __restrict__ out) {
  __shared__ _Float16 smem[12288];          // A 8192 + B 4096
  _Float16* As = smem;
  _Float16* Bs = smem + 8192;

  const int tid = threadIdx.x;
  const int w = tid >> 6, lane = tid & 63;
  const int l4 = lane & 15, quad = lane >> 4;
  const int wm = w & 1, wn = w >> 1;

  const int bid = blockIdx.x;
  const int xcd = bid & 7, li = bid >> 3;   // li in 0..127
  const int n_l = li >> 3, m_l = li & 7;    // n_l 0..15, m_l 0..7
  const int m0 = (xcd * 8 + m_l) * 128;
  const int n0 = n_l * 64;

  const floatx4 zero = {0.f, 0.f, 0.f, 0.f};
  floatx4 acc[4][2];
#pragma unroll
  for (int i = 0; i < 4; ++i)
#pragma unroll
    for (int j = 0; j < 2; ++j) acc[i][j] = zero;

  for (int kt = 0; kt < 16; ++kt) {
    const int k0 = kt * 64;
#pragma unroll
    for (int i = 0; i < 4; ++i) {           // A: 128 rows x 8 chunks
      const int p = i * 256 + tid;
      const int r = p >> 3;
      const int c = (p & 7) ^ (r & 7);
      async_copy16(A + (m0 + r) * 1024 + k0 + c * 8, As + (i * 256 + w * 64) * 8);
    }
#pragma unroll
    for (int i = 0; i < 2; ++i) {           // B: 64 rows x 8 chunks
      const int p = i * 256 + tid;
      const int r = p >> 3;
      const int c = (p & 7) ^ (r & 7);
      async_copy16(B + (n0 + r) * 1024 + k0 + c * 8, Bs + (i * 256 + w * 64) * 8);
    }
    __syncthreads();
#pragma unroll
    for (int ks = 0; ks < 2; ++ks) {
      half8 af[4], bf[2];
#pragma unroll
      for (int mt = 0; mt < 4; ++mt)
        af[mt] = *(const half8*)(As + (wm * 64 + mt * 16 + l4) * 64 +
                                 (((ks * 4 + quad) ^ (l4 & 7)) * 8));
#pragma unroll
      for (int nt = 0; nt < 2; ++nt)
        bf[nt] = *(const half8*)(Bs + (wn * 32 + nt * 16 + l4) * 64 +
                                 (((ks * 4 + quad) ^ (l4 & 7)) * 8));
#pragma unroll
      for (int mt = 0; mt < 4; ++mt)
#pragma unroll
        for (int nt = 0; nt < 2; ++nt)
          acc[mt][nt] = __builtin_amdgcn_mfma_f32_16x16x32_f16(af[mt], bf[nt], acc[mt][nt], 0, 0, 0);
    }
    __syncthreads();
  }

#pragma unroll
  for (int nt = 0; nt < 2; ++nt) {
    const int n = n0 + wn * 32 + nt * 16 + l4;
    const float bval = bias[n];
#pragma unroll
    for (int mt = 0; mt < 4; ++mt)
#pragma unroll
      for (int r = 0; r < 4; ++r) {
        const int m = m0 + wm * 64 + mt * 16 + quad * 4 + r;
        out[m * 1024 + n] = acc[mt][nt][r] + bval;
      }
  }
}

// ---------------------------------------------------------------- attention
// R10 structure (verified win) + T5 setprio around MFMA clusters.
// S^T formulation; 256 q/block; double-buffered KV staging, stage-ahead +
// vmcnt(8); raw barriers; exact per-wave band skip/mask; XCD-grouped bh.
__global__ __launch_bounds__(256, 2) void attn_kernel(
    const _Float16* __restrict__ qg, const _Float16* __restrict__ kg,
    const _Float16* __restrict__ vtg, _Float16* __restrict__ ctx) {
  __shared__ _Float16 Ks[2][128 * 64];   // [buf][key][d]
  __shared__ _Float16 Vs[2][64 * 128];   // [buf][d][key] (from vt)

  const int tid = threadIdx.x;
  const int w = tid >> 6, lane = tid & 63;
  const int l4 = lane & 15, quad = lane >> 4;

  const int bid = blockIdx.x;
  const int xcd = bid & 7, li = bid >> 3;   // li 0..63
  const int bh = xcd * 4 + (li >> 4);       // XCD owns 4 heads -> KV L2-fit
  const int q0 = (li & 15) * 256;

  const _Float16* qbh = qg + bh * 262144;
  const _Float16* kbh = kg + bh * 262144;
  const _Float16* vbh = vtg + bh * 262144;

  // Q as B-operand frags: query = q0 + sub*128 + w*32 + nt*16 + l4
  half8 qf[2][2][2];
#pragma unroll
  for (int sub = 0; sub < 2; ++sub)
#pragma unroll
    for (int nt = 0; nt < 2; ++nt)
#pragma unroll
      for (int ks = 0; ks < 2; ++ks)
        qf[sub][nt][ks] = *(const half8*)(qbh + (q0 + sub * 128 + w * 32 + nt * 16 + l4) * 64 +
                                          ks * 32 + quad * 8);

  const floatx4 zero = {0.f, 0.f, 0.f, 0.f};
  floatx4 OT[2][4][2];               // [sub][d-tile][q-tile]
  float l_st[2][2];                  // lane-local partial (this quad's keys)
#pragma unroll
  for (int sub = 0; sub < 2; ++sub) {
#pragma unroll
    for (int md = 0; md < 4; ++md)
#pragma unroll
      for (int nt = 0; nt < 2; ++nt) OT[sub][md][nt] = zero;
#pragma unroll
    for (int nt = 0; nt < 2; ++nt) l_st[sub][nt] = 0.f;
  }

  // valid kv-tile range: kv0(t) = q0 - 256 + t*128 in [0, 3968]
  const int tb = (q0 == 0) ? 2 : 0;
  const int te = (q0 == 3840) ? 3 : 5;

  // stage one 128-key tile (K + V^T slab) into buffer b_: 8 loads/thread.
  auto stage = [&](int b_, int kv0_) {
#pragma unroll
    for (int i = 0; i < 4; ++i) {
      const int p = i * 256 + tid;
      const int rk = p >> 3, ck = (p & 7) ^ (rk & 7);
      async_copy16(kbh + (kv0_ + rk) * 64 + ck * 8, &Ks[b_][(i * 256 + w * 64) * 8]);
      const int rv = p >> 4, cv = (p & 15) ^ (rv & 7);
      async_copy16(vbh + rv * 4096 + kv0_ + cv * 8, &Vs[b_][(i * 256 + w * 64) * 8]);
    }
  };

  stage(tb & 1, q0 - 256 + tb * 128);

  for (int t = tb; t <= te; ++t) {
    const int kv0 = q0 - 256 + t * 128;
    if (t < te) {
      stage((t + 1) & 1, kv0 + 128);
      asm volatile("s_waitcnt vmcnt(8)" ::: "memory");  // tile t landed; t+1 in flight
    } else {
      asm volatile("s_waitcnt vmcnt(0)" ::: "memory");  // last tile: drain
    }
    __builtin_amdgcn_s_barrier();
    const _Float16* Kc = Ks[t & 1];
    const _Float16* Vc = Vs[t & 1];

#pragma unroll
    for (int sub = 0; sub < 2; ++sub) {
      const int qbase = q0 + sub * 128 + w * 32;   // this wave's 32 queries
#pragma unroll
      for (int hf = 0; hf < 2; ++hf) {
        const int kb = hf * 64;
        const int k_lo = kv0 + kb, k_hi = k_lo + 63;
        // wave-uniform: all 64 keys outside band for all 32 queries -> skip
        if (k_lo - (qbase + 31) > 256 || k_hi - qbase < -256) continue;
        const bool needm = (k_lo - (qbase + 31) < -256) || (k_hi - qbase > 256);

        floatx4 ST[4][2];
#pragma unroll
        for (int m = 0; m < 4; ++m)
#pragma unroll
          for (int nt = 0; nt < 2; ++nt) ST[m][nt] = zero;

        __builtin_amdgcn_s_setprio(1);      // T5: QK MFMA cluster
#pragma unroll
        for (int ks = 0; ks < 2; ++ks)
#pragma unroll
          for (int m = 0; m < 4; ++m) {
            const half8 kf = *(const half8*)(Kc + (kb + m * 16 + l4) * 64 +
                                             ((ks * 4 + quad) ^ (l4 & 7)) * 8);
#pragma unroll
            for (int nt = 0; nt < 2; ++nt)
              ST[m][nt] = __builtin_amdgcn_mfma_f32_16x16x32_f16(kf, qf[sub][nt][ks], ST[m][nt], 0, 0, 0);
          }
        __builtin_amdgcn_s_setprio(0);

        if (needm) {  // band mask |key - query| <= 256
#pragma unroll
          for (int m = 0; m < 4; ++m)
#pragma unroll
            for (int r = 0; r < 4; ++r) {
              const int key = kv0 + kb + m * 16 + quad * 4 + r;
#pragma unroll
              for (int nt = 0; nt < 2; ++nt) {
                const int d = key - (qbase + nt * 16 + l4);
                if (d < -256 || d > 256) ST[m][nt][r] = -1e30f;
              }
            }
        }

        // P = exp2(S - 4); lane-local l accumulation (no max, no rescale)
#pragma unroll
        for (int nt = 0; nt < 2; ++nt) {
          float rs = 0.f;
#pragma unroll
          for (int m = 0; m < 4; ++m)
#pragma unroll
            for (int r = 0; r < 4; ++r) {
              const float pv = exp2f(ST[m][nt][r] - 4.0f);
              ST[m][nt][r] = pv;
              rs += pv;
            }
          l_st[sub][nt] += rs;
        }

        // O^T += V^T P^T; P B-frag = packed ST C-frag (k=quad*4+j)
        __builtin_amdgcn_s_setprio(1);      // T5: PV pack+MFMA cluster
#pragma unroll
        for (int m = 0; m < 4; ++m) {
          half4v pb[2];
#pragma unroll
          for (int nt = 0; nt < 2; ++nt) {
            const auto lo = __builtin_amdgcn_cvt_pkrtz(ST[m][nt][0], ST[m][nt][1]);
            const auto hi = __builtin_amdgcn_cvt_pkrtz(ST[m][nt][2], ST[m][nt][3]);
            pb[nt][0] = (_Float16)lo[0]; pb[nt][1] = (_Float16)lo[1];
            pb[nt][2] = (_Float16)hi[0]; pb[nt][3] = (_Float16)hi[1];
          }
#pragma unroll
          for (int md = 0; md < 4; ++md) {
            const half4v vf = *(const half4v*)(Vc + (md * 16 + l4) * 128 +
                                               (((hf * 8 + m * 2 + (quad >> 1)) ^ (l4 & 7)) * 8 +
                                                (quad & 1) * 4));
#pragma unroll
            for (int nt = 0; nt < 2; ++nt)
              OT[sub][md][nt] = __builtin_amdgcn_mfma_f32_16x16x16f16(vf, pb[nt], OT[sub][md][nt], 0, 0, 0);
          }
        }
        __builtin_amdgcn_s_setprio(0);
      }
    }

    if (t < te) {
      // trailing barrier: my ds_reads of this buffer must retire before any
      // wave stages into it next iteration. NOT __syncthreads (vmcnt drain).
      asm volatile("s_waitcnt lgkmcnt(0)" ::: "memory");
      __builtin_amdgcn_sched_barrier(0);
      __builtin_amdgcn_s_barrier();
    }
  }

  // epilogue: reduce l across quads (keys were quad-distributed), then scale.
  const int b = bh >> 4, hh = bh & 15;
#pragma unroll
  for (int sub = 0; sub < 2; ++sub)
#pragma unroll
    for (int nt = 0; nt < 2; ++nt) {
      float lt = l_st[sub][nt];
      lt += __shfl_xor(lt, 16);
      lt += __shfl_xor(lt, 32);
      const float inv_l = 1.f / lt;
      const int s = q0 + sub * 128 + w * 32 + nt * 16 + l4;
#pragma unroll
      for (int md = 0; md < 4; ++md) {
        half4v o;
#pragma unroll
        for (int r = 0; r < 4; ++r) o[r] = (_Float16)(OT[sub][md][nt][r] * inv_l);
        *(half4v*)(ctx + (b * 4096 + s) * 1024 + hh * 64 + md * 16 + quad * 4) = o;
      }
    }
}

// ---------------------------------------------------------------- launch
extern "C" void kernel_launch(void* const* d_in, const int* in_sizes, int n_in,
                              void* d_out, int out_size, void* d_ws, size_t ws_size,
                              hipStream_t stream) {
  const float* x  = (const float*)d_in[0];
  const float* Wq = (const float*)d_in[1];
  const float* bq = (const float*)d_in[2];
  const float* Wk = (const float*)d_in[3];
  const float* bk = (const float*)d_in[4];
  const float* Wv = (const float*)d_in[5];
  const float* bv = (const float*)d_in[6];
  const float* Wo = (const float*)d_in[7];
  const float* bo = (const float*)d_in[8];

  _Float16* ws   = (_Float16*)d_ws;       // all offsets in halfs
  _Float16* xh   = ws;                    // 8388608
  _Float16* wqh  = ws + 8388608;          // 1048576 each
  _Float16* wkh  = ws + 9437184;
  _Float16* wvh  = ws + 10485760;
  _Float16* woh  = ws + 11534336;
  _Float16* qh   = ws + 12582912;         // [b,h,s,d] fp16, rope+scale applied
  _Float16* kh   = ws + 20971520;         // [b,h,s,d] fp16, rope applied
  _Float16* vth  = ws + 29360128;         // [b,h,d,s] fp16 (written directly)
  _Float16* ctxh = xh;                    // reuse: x dead after QKV GEMM

  convert_kernel<<<12288, 256, 0, stream>>>(x, Wq, Wk, Wv, Wo, ws);
  gemm_qkv_kernel<<<1536, 256, 0, stream>>>(xh, wqh, wkh, wvh,
                                            bq, bk, bv, qh, kh, vth);
  attn_kernel<<<512, 256, 0, stream>>>(qh, kh, vth, ctxh);
  gemm_out_kernel<<<1024, 256, 0, stream>>>(ctxh, woh, bo, (float*)d_out);
}

// Round 7
// 227.325 us; speedup vs baseline: 1.0388x; 1.0156x over previous
//
#include <hip/hip_runtime.h>

// LongformerAttention on MI355X (gfx950), fp16 MFMA pipeline, round 14.
// R14: R13's two changes both reverted (same-session A/B: +4.9us worse).
// Base = R10 (best measured, 226.0us). One change: attn PV upgraded from
// K=16 to K=32 MFMA via a CUSTOM K-SLOT ORDER. MFMA sums over k, so the
// slot->key map is arbitrary if A and B agree: slot(quad,j) -> key
// g*32 + (j>>2)*16 + quad*4 + (j&3). With this order the K=32 B-operand
// (P^T) is exactly the lane's OWN ST C-fragment values (zero shuffles; the
// same 16 cvt_pkrtz packs, rearranged), and the A-operand (V^T) is two
// ds_read_b64 at chunks (hf*8+g*4+(quad>>1)) and +2 under the existing
// swizzle. PV MFMA count per 64-key half-tile: 32x(16x16x16) ->
// 16x(16x16x32), ~40% fewer PV MFMA cycles; LDS traffic unchanged; C-layout
// identical (col=l4, row=quad*4+r) so OT/epilogue untouched.
// GEMMs/convert = R10 verbatim (qkv anchor: 66us, MfmaUtil 33%, VGPR 64).

typedef _Float16 half8 __attribute__((ext_vector_type(8)));
typedef _Float16 half4v __attribute__((ext_vector_type(4)));
typedef float floatx4 __attribute__((ext_vector_type(4)));

typedef __attribute__((address_space(3))) unsigned int lds_u32;
typedef const __attribute__((address_space(1))) unsigned int glb_u32;

__device__ __forceinline__ void async_copy16(const void* g, void* l) {
  // global -> LDS direct, 16 B/lane. LDS dest = wave-uniform base + lane*16.
  __builtin_amdgcn_global_load_lds((glb_u32*)g, (lds_u32*)l, 16, 0, 0);
}

// ---------------------------------------------------------------- convert
__global__ __launch_bounds__(256) void convert_kernel(
    const float* __restrict__ x, const float* __restrict__ wq,
    const float* __restrict__ wk, const float* __restrict__ wv,
    const float* __restrict__ wo, _Float16* __restrict__ dst) {
  const int e0 = (blockIdx.x * 256 + threadIdx.x) * 4;
  const float* src; int off;
  if      (e0 <  8388608) { src = x;  off = e0; }
  else if (e0 <  9437184) { src = wq; off = e0 -  8388608; }
  else if (e0 < 10485760) { src = wk; off = e0 -  9437184; }
  else if (e0 < 11534336) { src = wv; off = e0 - 10485760; }
  else                    { src = wo; off = e0 - 11534336; }
  const float4 f = *(const float4*)(src + off);
  half4v h;
  h[0] = (_Float16)f.x; h[1] = (_Float16)f.y;
  h[2] = (_Float16)f.z; h[3] = (_Float16)f.w;
  *(half4v*)(dst + e0) = h;
}

// ---------------------------------------------------------------- QKV GEMM
// R7 structure (proven: MfmaUtil 33%, conflicts = epilogue-only).
// out[m,n] = sum_k A[m,k]*W[n,k] + bias[n]; RoPE fused in epilogue for q,k
// (pair (n,n^1) in adjacent l4 lanes -> __shfl_xor(val,1)); q scaled log2e/8.
// z==2 (V): epilogue LDS tile stored transposed, output written as V^T
// [bh][d][s] directly.
__global__ __launch_bounds__(256, 2) void gemm_qkv_kernel(
    const _Float16* __restrict__ A, const _Float16* __restrict__ w0,
    const _Float16* __restrict__ w1, const _Float16* __restrict__ w2,
    const float* __restrict__ b0, const float* __restrict__ b1,
    const float* __restrict__ b2, _Float16* __restrict__ o0,
    _Float16* __restrict__ o1, _Float16* __restrict__ o2) {
  __shared__ _Float16 smem[17408];          // staging 32 KB / epi tile 33.8 KB
  _Float16* As = smem;                      // [128][64] chunk-swizzled
  _Float16* Bs = smem + 8192;

  const int tid = threadIdx.x;
  const int w = tid >> 6, lane = tid & 63;
  const int l4 = lane & 15, quad = lane >> 4;
  const int wm = w & 1, wn = w >> 1;

  const int bid = blockIdx.x;
  const int xcd = bid & 7, li = bid >> 3;   // li in 0..191
  const int z = li >> 6, r_ = li & 63;
  const int n_l = r_ >> 3, m_l = r_ & 7;
  const int m0 = (xcd * 8 + m_l) * 128;
  const int n0 = n_l * 128;

  const _Float16* B; const float* bias; _Float16* out;
  if (z == 0)      { B = w0; bias = b0; out = o0; }
  else if (z == 1) { B = w1; bias = b1; out = o1; }
  else             { B = w2; bias = b2; out = o2; }
  const bool dorope = z < 2;
  const float scl = (z == 0) ? 0.18033688f : 1.0f;  // log2e/8

  const floatx4 zero = {0.f, 0.f, 0.f, 0.f};
  floatx4 acc[4][4];
#pragma unroll
  for (int i = 0; i < 4; ++i)
#pragma unroll
    for (int j = 0; j < 4; ++j) acc[i][j] = zero;

  for (int kt = 0; kt < 16; ++kt) {
    const int k0 = kt * 64;
#pragma unroll
    for (int i = 0; i < 4; ++i) {
      const int p = i * 256 + tid;          // 128 rows x 8 chunks
      const int r = p >> 3;
      const int c = (p & 7) ^ (r & 7);      // 3-bit XOR chunk swizzle
      async_copy16(A + (m0 + r) * 1024 + k0 + c * 8, As + (i * 256 + w * 64) * 8);
      async_copy16(B + (n0 + r) * 1024 + k0 + c * 8, Bs + (i * 256 + w * 64) * 8);
    }
    __syncthreads();
#pragma unroll
    for (int ks = 0; ks < 2; ++ks) {
      half8 af[4], bf[4];
#pragma unroll
      for (int mt = 0; mt < 4; ++mt)
        af[mt] = *(const half8*)(As + (wm * 64 + mt * 16 + l4) * 64 +
                                 (((ks * 4 + quad) ^ (l4 & 7)) * 8));
#pragma unroll
      for (int nt = 0; nt < 4; ++nt)
        bf[nt] = *(const half8*)(Bs + (wn * 64 + nt * 16 + l4) * 64 +
                                 (((ks * 4 + quad) ^ (l4 & 7)) * 8));
#pragma unroll
      for (int mt = 0; mt < 4; ++mt)
#pragma unroll
        for (int nt = 0; nt < 4; ++nt)
          acc[mt][nt] = __builtin_amdgcn_mfma_f32_16x16x32_f16(af[mt], bf[nt], acc[mt][nt], 0, 0, 0);
    }
    __syncthreads();
  }

  // epilogue: bias (+RoPE) in C-layout -> LDS tile -> coalesced half8 stores.
  // q,k: tile[m][n], store [bh][s][d]. V: tile[n][m], store V^T [bh][d][s].
  _Float16* tile = smem;                    // [128][132]
#pragma unroll
  for (int nt = 0; nt < 4; ++nt) {
    const int n = n0 + wn * 64 + nt * 16 + l4;
    const float bval = bias[n];
    const int hh = n >> 6;
    float c_ = 1.f, ss = 0.f;
    if (dorope) {
      const float freq = __expf((float)(n & 31) * -0.28782314f);  // ln(1e4)/32
      float s_;
      __sincosf((float)hh * freq, &s_, &c_);
      ss = (n & 1) ? s_ : -s_;
    }
#pragma unroll
    for (int mt = 0; mt < 4; ++mt)
#pragma unroll
      for (int r = 0; r < 4; ++r) {
        float val = acc[mt][nt][r] + bval;
        const float prt = __shfl_xor(val, 1);
        if (dorope) val = (val * c_ + prt * ss) * scl;
        const int ml = wm * 64 + mt * 16 + quad * 4 + r;
        const int nl = wn * 64 + nt * 16 + l4;
        if (z == 2) tile[nl * 132 + ml] = (_Float16)val;   // transposed
        else        tile[ml * 132 + nl] = (_Float16)val;
      }
  }
  __syncthreads();
  if (z == 2) {
#pragma unroll
    for (int j = 0; j < 8; ++j) {
      const int idx = j * 256 + tid;        // 128 d-rows x 16 s-chunks
      const int row = idx >> 4, cb = idx & 15;
      const int n = n0 + row, hh = n >> 6, dd = n & 63;
      const int m = m0 + cb * 8, bb = m >> 12, s = m & 4095;
      const half8 vals = *(const half8*)(tile + row * 132 + cb * 8);
      *(half8*)(out + (bb * 16 + hh) * 262144 + dd * 4096 + s) = vals;
    }
  } else {
#pragma unroll
    for (int j = 0; j < 8; ++j) {
      const int idx = j * 256 + tid;        // 128 s-rows x 16 d-chunks
      const int row = idx >> 4, cb = idx & 15;
      const int n = n0 + cb * 8, hh = n >> 6, dd = n & 63;
      const int m = m0 + row, bb = m >> 12, s = m & 4095;
      const half8 vals = *(const half8*)(tile + row * 132 + cb * 8);
      *(half8*)(out + ((bb * 16 + hh) * 4096 + s) * 64 + dd) = vals;
    }
  }
}

// ---------------------------------------------------------------- out GEMM
// R10/R7 structure verbatim (128x128, grid 512).
__global__ __launch_bounds__(256, 2) void gemm_out_kernel(
    const _Float16* __restrict__ A, const _Float16* __restrict__ B,
    const float* __restrict__ bias, float* __restrict__ out) {
  __shared__ _Float16 smem[16384];
  _Float16* As = smem;
  _Float16* Bs = smem + 8192;

  const int tid = threadIdx.x;
  const int w = tid >> 6, lane = tid & 63;
  const int l4 = lane & 15, quad = lane >> 4;
  const int wm = w & 1, wn = w >> 1;

  const int bid = blockIdx.x;
  const int xcd = bid & 7, li = bid >> 3;   // li in 0..63
  const int n_l = li >> 3, m_l = li & 7;
  const int m0 = (xcd * 8 + m_l) * 128;
  const int n0 = n_l * 128;

  const floatx4 zero = {0.f, 0.f, 0.f, 0.f};
  floatx4 acc[4][4];
#pragma unroll
  for (int i = 0; i < 4; ++i)
#pragma unroll
    for (int j = 0; j < 4; ++j) acc[i][j] = zero;

  for (int kt = 0; kt < 16; ++kt) {
    const int k0 = kt * 64;
#pragma unroll
    for (int i = 0; i < 4; ++i) {
      const int p = i * 256 + tid;
      const int r = p >> 3;
      const int c = (p & 7) ^ (r & 7);
      async_copy16(A + (m0 + r) * 1024 + k0 + c * 8, As + (i * 256 + w * 64) * 8);
      async_copy16(B + (n0 + r) * 1024 + k0 + c * 8, Bs + (i * 256 + w * 64) * 8);
    }
    __syncthreads();
#pragma unroll
    for (int ks = 0; ks < 2; ++ks) {
      half8 af[4], bf[4];
#pragma unroll
      for (int mt = 0; mt < 4; ++mt)
        af[mt] = *(const half8*)(As + (wm * 64 + mt * 16 + l4) * 64 +
                                 (((ks * 4 + quad) ^ (l4 & 7)) * 8));
#pragma unroll
      for (int nt = 0; nt < 4; ++nt)
        bf[nt] = *(const half8*)(Bs + (wn * 64 + nt * 16 + l4) * 64 +
                                 (((ks * 4 + quad) ^ (l4 & 7)) * 8));
#pragma unroll
      for (int mt = 0; mt < 4; ++mt)
#pragma unroll
        for (int nt = 0; nt < 4; ++nt)
          acc[mt][nt] = __builtin_amdgcn_mfma_f32_16x16x32_f16(af[mt], bf[nt], acc[mt][nt], 0, 0, 0);
    }
    __syncthreads();
  }

#pragma unroll
  for (int nt = 0; nt < 4; ++nt) {
    const int n = n0 + wn * 64 + nt * 16 + l4;
    const float bval = bias[n];
#pragma unroll
    for (int mt = 0; mt < 4; ++mt)
#pragma unroll
      for (int r = 0; r < 4; ++r) {
        const int m = m0 + wm * 64 + mt * 16 + quad * 4 + r;
        out[m * 1024 + n] = acc[mt][nt][r] + bval;
      }
  }
}

// ---------------------------------------------------------------- attention
// R10 structure (verified win): S^T formulation; 256 q/block; double-buffered
// KV staging, stage-ahead + vmcnt(8); raw barriers; exact per-wave band
// skip/mask; XCD-grouped bh. R14: PV via K=32 MFMA with custom k-slot order
// (see header) — B-frag lane-local, A-frag = two ds_read_b64, same C layout.
__global__ __launch_bounds__(256, 2) void attn_kernel(
    const _Float16* __restrict__ qg, const _Float16* __restrict__ kg,
    const _Float16* __restrict__ vtg, _Float16* __restrict__ ctx) {
  __shared__ _Float16 Ks[2][128 * 64];   // [buf][key][d]
  __shared__ _Float16 Vs[2][64 * 128];   // [buf][d][key] (from vt)

  const int tid = threadIdx.x;
  const int w = tid >> 6, lane = tid & 63;
  const int l4 = lane & 15, quad = lane >> 4;

  const int bid = blockIdx.x;
  const int xcd = bid & 7, li = bid >> 3;   // li 0..63
  const int bh = xcd * 4 + (li >> 4);       // XCD owns 4 heads -> KV L2-fit
  const int q0 = (li & 15) * 256;

  const _Float16* qbh = qg + bh * 262144;
  const _Float16* kbh = kg + bh * 262144;
  const _Float16* vbh = vtg + bh * 262144;

  // Q as B-operand frags: query = q0 + sub*128 + w*32 + nt*16 + l4
  half8 qf[2][2][2];
#pragma unroll
  for (int sub = 0; sub < 2; ++sub)
#pragma unroll
    for (int nt = 0; nt < 2; ++nt)
#pragma unroll
      for (int ks = 0; ks < 2; ++ks)
        qf[sub][nt][ks] = *(const half8*)(qbh + (q0 + sub * 128 + w * 32 + nt * 16 + l4) * 64 +
                                          ks * 32 + quad * 8);

  const floatx4 zero = {0.f, 0.f, 0.f, 0.f};
  floatx4 OT[2][4][2];               // [sub][d-tile][q-tile]
  float l_st[2][2];                  // lane-local partial (this quad's keys)
#pragma unroll
  for (int sub = 0; sub < 2; ++sub) {
#pragma unroll
    for (int md = 0; md < 4; ++md)
#pragma unroll
      for (int nt = 0; nt < 2; ++nt) OT[sub][md][nt] = zero;
#pragma unroll
    for (int nt = 0; nt < 2; ++nt) l_st[sub][nt] = 0.f;
  }

  // valid kv-tile range: kv0(t) = q0 - 256 + t*128 in [0, 3968]
  const int tb = (q0 == 0) ? 2 : 0;
  const int te = (q0 == 3840) ? 3 : 5;

  // stage one 128-key tile (K + V^T slab) into buffer b_: 8 loads/thread.
  auto stage = [&](int b_, int kv0_) {
#pragma unroll
    for (int i = 0; i < 4; ++i) {
      const int p = i * 256 + tid;
      const int rk = p >> 3, ck = (p & 7) ^ (rk & 7);
      async_copy16(kbh + (kv0_ + rk) * 64 + ck * 8, &Ks[b_][(i * 256 + w * 64) * 8]);
      const int rv = p >> 4, cv = (p & 15) ^ (rv & 7);
      async_copy16(vbh + rv * 4096 + kv0_ + cv * 8, &Vs[b_][(i * 256 + w * 64) * 8]);
    }
  };

  stage(tb & 1, q0 - 256 + tb * 128);

  for (int t = tb; t <= te; ++t) {
    const int kv0 = q0 - 256 + t * 128;
    if (t < te) {
      stage((t + 1) & 1, kv0 + 128);
      asm volatile("s_waitcnt vmcnt(8)" ::: "memory");  // tile t landed; t+1 in flight
    } else {
      asm volatile("s_waitcnt vmcnt(0)" ::: "memory");  // last tile: drain
    }
    __builtin_amdgcn_s_barrier();
    const _Float16* Kc = Ks[t & 1];
    const _Float16* Vc = Vs[t & 1];

#pragma unroll
    for (int sub = 0; sub < 2; ++sub) {
      const int qbase = q0 + sub * 128 + w * 32;   // this wave's 32 queries
#pragma unroll
      for (int hf = 0; hf < 2; ++hf) {
        const int kb = hf * 64;
        const int k_lo = kv0 + kb, k_hi = k_lo + 63;
        // wave-uniform: all 64 keys outside band for all 32 queries -> skip
        if (k_lo - (qbase + 31) > 256 || k_hi - qbase < -256) continue;
        const bool needm = (k_lo - (qbase + 31) < -256) || (k_hi - qbase > 256);

        floatx4 ST[4][2];
#pragma unroll
        for (int m = 0; m < 4; ++m)
#pragma unroll
          for (int nt = 0; nt < 2; ++nt) ST[m][nt] = zero;
#pragma unroll
        for (int ks = 0; ks < 2; ++ks)
#pragma unroll
          for (int m = 0; m < 4; ++m) {
            const half8 kf = *(const half8*)(Kc + (kb + m * 16 + l4) * 64 +
                                             ((ks * 4 + quad) ^ (l4 & 7)) * 8);
#pragma unroll
            for (int nt = 0; nt < 2; ++nt)
              ST[m][nt] = __builtin_amdgcn_mfma_f32_16x16x32_f16(kf, qf[sub][nt][ks], ST[m][nt], 0, 0, 0);
          }

        if (needm) {  // band mask |key - query| <= 256
#pragma unroll
          for (int m = 0; m < 4; ++m)
#pragma unroll
            for (int r = 0; r < 4; ++r) {
              const int key = kv0 + kb + m * 16 + quad * 4 + r;
#pragma unroll
              for (int nt = 0; nt < 2; ++nt) {
                const int d = key - (qbase + nt * 16 + l4);
                if (d < -256 || d > 256) ST[m][nt][r] = -1e30f;
              }
            }
        }

        // P = exp2(S - 4); lane-local l accumulation (no max, no rescale)
#pragma unroll
        for (int nt = 0; nt < 2; ++nt) {
          float rs = 0.f;
#pragma unroll
          for (int m = 0; m < 4; ++m)
#pragma unroll
            for (int r = 0; r < 4; ++r) {
              const float pv = exp2f(ST[m][nt][r] - 4.0f);
              ST[m][nt][r] = pv;
              rs += pv;
            }
          l_st[sub][nt] += rs;
        }

        // O^T += V^T P^T, K=32 MFMA, custom k-order:
        // slot(quad,j) -> key g*32 + (j>>2)*16 + quad*4 + (j&3), applied to
        // BOTH operands. B-frag = lane's own ST packs (zero shuffles);
        // A-frag = two ds_read_b64 at chunks (hf*8+g*4+(quad>>1)) and +2.
#pragma unroll
        for (int g = 0; g < 2; ++g) {
          half8 pb[2];
#pragma unroll
          for (int nt = 0; nt < 2; ++nt) {
            const auto l0 = __builtin_amdgcn_cvt_pkrtz(ST[2 * g][nt][0], ST[2 * g][nt][1]);
            const auto h0 = __builtin_amdgcn_cvt_pkrtz(ST[2 * g][nt][2], ST[2 * g][nt][3]);
            const auto l1 = __builtin_amdgcn_cvt_pkrtz(ST[2 * g + 1][nt][0], ST[2 * g + 1][nt][1]);
            const auto h1 = __builtin_amdgcn_cvt_pkrtz(ST[2 * g + 1][nt][2], ST[2 * g + 1][nt][3]);
            pb[nt][0] = (_Float16)l0[0]; pb[nt][1] = (_Float16)l0[1];
            pb[nt][2] = (_Float16)h0[0]; pb[nt][3] = (_Float16)h0[1];
            pb[nt][4] = (_Float16)l1[0]; pb[nt][5] = (_Float16)l1[1];
            pb[nt][6] = (_Float16)h1[0]; pb[nt][7] = (_Float16)h1[1];
          }
#pragma unroll
          for (int md = 0; md < 4; ++md) {
            const int vrow = (md * 16 + l4) * 128;
            const half4v va = *(const half4v*)(Vc + vrow +
                ((hf * 8 + g * 4 + (quad >> 1)) ^ (l4 & 7)) * 8 + (quad & 1) * 4);
            const half4v vb = *(const half4v*)(Vc + vrow +
                ((hf * 8 + g * 4 + 2 + (quad >> 1)) ^ (l4 & 7)) * 8 + (quad & 1) * 4);
            half8 vf;
            vf[0] = va[0]; vf[1] = va[1]; vf[2] = va[2]; vf[3] = va[3];
            vf[4] = vb[0]; vf[5] = vb[1]; vf[6] = vb[2]; vf[7] = vb[3];
#pragma unroll
            for (int nt = 0; nt < 2; ++nt)
              OT[sub][md][nt] = __builtin_amdgcn_mfma_f32_16x16x32_f16(vf, pb[nt], OT[sub][md][nt], 0, 0, 0);
          }
        }
      }
    }

    if (t < te) {
      // trailing barrier: my ds_reads of this buffer must retire before any
      // wave stages into it next iteration. NOT __syncthreads (vmcnt drain).
      asm volatile("s_waitcnt lgkmcnt(0)" ::: "memory");
      __builtin_amdgcn_sched_barrier(0);
      __builtin_amdgcn_s_barrier();
    }
  }

  // epilogue: reduce l across quads (keys were quad-distributed), then scale.
  const int b = bh >> 4, hh = bh & 15;
#pragma unroll
  for (int sub = 0; sub < 2; ++sub)
#pragma unroll
    for (int nt = 0; nt < 2; ++nt) {
      float lt = l_st[sub][nt];
      lt += __shfl_xor(lt, 16);
      lt += __shfl_xor(lt, 32);
      const float inv_l = 1.f / lt;
      const int s = q0 + sub * 128 + w * 32 + nt * 16 + l4;
#pragma unroll
      for (int md = 0; md < 4; ++md) {
        half4v o;
#pragma unroll
        for (int r = 0; r < 4; ++r) o[r] = (_Float16)(OT[sub][md][nt][r] * inv_l);
        *(half4v*)(ctx + (b * 4096 + s) * 1024 + hh * 64 + md * 16 + quad * 4) = o;
      }
    }
}

// ---------------------------------------------------------------- launch
extern "C" void kernel_launch(void* const* d_in, const int* in_sizes, int n_in,
                              void* d_out, int out_size, void* d_ws, size_t ws_size,
                              hipStream_t stream) {
  const float* x  = (const float*)d_in[0];
  const float* Wq = (const float*)d_in[1];
  const float* bq = (const float*)d_in[2];
  const float* Wk = (const float*)d_in[3];
  const float* bk = (const float*)d_in[4];
  const float* Wv = (const float*)d_in[5];
  const float* bv = (const float*)d_in[6];
  const float* Wo = (const float*)d_in[7];
  const float* bo = (const float*)d_in[8];

  _Float16* ws   = (_Float16*)d_ws;       // all offsets in halfs
  _Float16* xh   = ws;                    // 8388608
  _Float16* wqh  = ws + 8388608;          // 1048576 each
  _Float16* wkh  = ws + 9437184;
  _Float16* wvh  = ws + 10485760;
  _Float16* woh  = ws + 11534336;
  _Float16* qh   = ws + 12582912;         // [b,h,s,d] fp16, rope+scale applied
  _Float16* kh   = ws + 20971520;         // [b,h,s,d] fp16, rope applied
  _Float16* vth  = ws + 29360128;         // [b,h,d,s] fp16 (written directly)
  _Float16* ctxh = xh;                    // reuse: x dead after QKV GEMM

  convert_kernel<<<12288, 256, 0, stream>>>(x, Wq, Wk, Wv, Wo, ws);
  gemm_qkv_kernel<<<1536, 256, 0, stream>>>(xh, wqh, wkh, wvh,
                                            bq, bk, bv, qh, kh, vth);
  attn_kernel<<<512, 256, 0, stream>>>(qh, kh, vth, ctxh);
  gemm_out_kernel<<<512, 256, 0, stream>>>(ctxh, woh, bo, (float*)d_out);
}